// Round 7
// baseline (186.488 us; speedup 1.0000x reference)
//
#include <hip/hip_runtime.h>
#include <hip/hip_bf16.h>

// B=32, S=2048, D=1024, C=256
//   top[b,s] = max_c sum_d (latent[c,d]*att_diag[d]) * (tm*embeds[b,s,d] + pos_table[rel+64,d])
//   p = softmax_s(top*m + (m-1)*NEG);  ctx[b,d] = tok_diag[d] * sum_s embeds*p
//
// Pass 1: split-fp16 MFMA (3 terms: hh + h*lo + lo*h). pos folded out:
//   scores = (tm*W)*e + WP[c,pid],  WP = W*pos_table^T (f32, exact).
// Round-4 skeleton: 256 thr / 4 waves / 128 tokens per block; wave owns all
// 16 c-tiles x 2 token sets (acc = 128 VGPR, launch_bounds(256,2), no spill).
// W staged once per block per kc via global_load_lds into dbuf LDS (64 KB,
// 2 blocks/CU). NEW: e-prefetch via two register sets, issued at the TOP of
// each iteration so the pre-barrier vmcnt drain is fully covered (T14).
//
// ws: w f16 1MB | wpt 256K | top 256K | probs 256K | partial 2M

#define HC 64
#define NEGV 1000000000000.0f

constexpr int Bb = 32, Ss = 2048, Dd = 1024, Cc = 256;
constexpr int NKC = 32;                 // k-chunks of 32
constexpr int CT = Cc / 16;             // 16 c-tiles
constexpr int NSPLIT = 16, SCHUNK = Ss / NSPLIT;

typedef _Float16 f16x8 __attribute__((ext_vector_type(8)));
typedef float    f32x4 __attribute__((ext_vector_type(4)));

// ---------------- Pass 0a: W' = tm*latent*att_diag -> fp16 hi/lo chunks ----
// layout: w[kc][part][ct][lane][8], chunk = 16384 f16 = 32KB
// A-frag map: lane = (c%16) + 16*g holds A[c][k = kc*32 + 8g + i]
__global__ __launch_bounds__(256) void k_prep_w(
    const float* __restrict__ latent, const float* __restrict__ att_diag,
    const float* __restrict__ tok_mult, _Float16* __restrict__ w)
{
    const int idx = blockIdx.x * 256 + threadIdx.x;   // c*Dd + k
    const int c = idx >> 10, k = idx & 1023;
    const float wv = tok_mult[0] * latent[idx] * att_diag[k];
    const _Float16 h  = (_Float16)wv;
    const _Float16 lo = (_Float16)(wv - (float)h);
    const int kc = k >> 5, g = (k >> 3) & 3, i = k & 7;
    const int lane = (c & 15) + 16 * g, ct = c >> 4;
    const size_t base = (size_t)kc * 16384 + (size_t)ct * 512 + lane * 8 + i;
    w[base]        = h;
    w[base + 8192] = lo;
}

// ---------------- Pass 0b: WP[pid][c] = sum_d latent[c,d]*att[d]*pos[pid,d]
__global__ __launch_bounds__(256) void k_wp(
    const float* __restrict__ latent, const float* __restrict__ att_diag,
    const float* __restrict__ pos_table, float* __restrict__ wpt)
{
    __shared__ float pa[1024];
    const int pid = blockIdx.x;        // 0..131
    const int t = threadIdx.x;
    {
        f32x4 p4 = *(const f32x4*)(pos_table + (size_t)pid * Dd + t * 4);
        f32x4 a4 = *(const f32x4*)(att_diag + t * 4);
        *(f32x4*)&pa[t * 4] = p4 * a4;
    }
    __syncthreads();
    const int wv = t >> 6, l = t & 63;
    float pav[16];
    #pragma unroll
    for (int q = 0; q < 4; q++) *(f32x4*)&pav[q * 4] = *(const f32x4*)&pa[l * 16 + q * 4];
    for (int c = wv; c < Cc; c += 4) {
        const float* lrow = latent + (size_t)c * Dd + l * 16;
        float s = 0.f;
        #pragma unroll
        for (int q = 0; q < 4; q++) {
            f32x4 lv = *(const f32x4*)(lrow + q * 4);
            s = fmaf(lv[0], pav[q * 4 + 0], s);
            s = fmaf(lv[1], pav[q * 4 + 1], s);
            s = fmaf(lv[2], pav[q * 4 + 2], s);
            s = fmaf(lv[3], pav[q * 4 + 3], s);
        }
        #pragma unroll
        for (int o = 32; o >= 1; o >>= 1) s += __shfl_xor(s, o);
        if (l == 0) wpt[pid * Cc + c] = s;
    }
}

// ---------------- Pass 1: scores via MFMA, max over c ----------------
__global__ __launch_bounds__(256, 2) void k_scores_mfma(
    const float* __restrict__ embeds,    // [B][S][D]
    const float* __restrict__ mask,      // [B][S]
    const int*   __restrict__ rel_ids,   // [B][S]
    const _Float16* __restrict__ w,      // [NKC][2][CT][64][8]
    const float* __restrict__ wpt,       // [132][256]
    float* __restrict__ top)             // [B][S]
{
    __shared__ _Float16 sbuf[2][16384];  // 2 x 32KB

    const int t  = threadIdx.x;
    const int wv = t >> 6;      // wave 0..3
    const int l  = t & 63;
    const int lr = l & 15;      // token within set / output col
    const int lg = l >> 4;      // k-group

    const int b  = blockIdx.x >> 4;          // 16 blocks of 128 tokens per batch
    const int s0 = (blockIdx.x & 15) * 128;

    const float* erow[2];
    int pid[2];
    #pragma unroll
    for (int st = 0; st < 2; st++) {
        const int tok = s0 + wv * 32 + st * 16 + lr;
        erow[st] = embeds + ((size_t)b * Ss + tok) * Dd;
        pid[st]  = rel_ids[b * Ss + tok] + HC;
    }

    f32x4 acc[CT][2];
    #pragma unroll
    for (int ct = 0; ct < CT; ct++)
        #pragma unroll
        for (int st = 0; st < 2; st++) acc[ct][st] = (f32x4){0.f, 0.f, 0.f, 0.f};

    // two e-register sets (rotation): issue next-kc loads at iteration top
    f32x4 eA0[2], eA1[2], eB0[2], eB1[2];
    auto loadEA = [&](int kc) {
        const int k0 = kc * 32 + lg * 8;
        #pragma unroll
        for (int st = 0; st < 2; st++) {
            eA0[st] = *(const f32x4*)(erow[st] + k0);
            eA1[st] = *(const f32x4*)(erow[st] + k0 + 4);
        }
    };
    auto loadEB = [&](int kc) {
        const int k0 = kc * 32 + lg * 8;
        #pragma unroll
        for (int st = 0; st < 2; st++) {
            eB0[st] = *(const f32x4*)(erow[st] + k0);
            eB1[st] = *(const f32x4*)(erow[st] + k0 + 4);
        }
    };

    // stage one 32KB W chunk: 32 x 1KB wave-chunks, 8 per wave
    auto stage = [&](int kc, _Float16* dst) {
        const _Float16* src = w + (size_t)kc * 16384;
        #pragma unroll
        for (int i = 0; i < 8; i++) {
            const int off = (i * 4 + wv) << 9;
            __builtin_amdgcn_global_load_lds(
                (const __attribute__((address_space(1))) void*)(src + off + l * 8),
                (__attribute__((address_space(3))) void*)(dst + off),
                16, 0, 0);
        }
    };

    auto splitMfma = [&](const f32x4* E0, const f32x4* E1, const _Float16* base) {
        f16x8 bh[2], bl[2];
        #pragma unroll
        for (int st = 0; st < 2; st++) {
            float e[8];
            *(f32x4*)&e[0] = E0[st]; *(f32x4*)&e[4] = E1[st];
            #pragma unroll
            for (int i = 0; i < 8; i++) {
                const _Float16 h = (_Float16)e[i];
                bh[st][i] = h;
                bl[st][i] = (_Float16)(e[i] - (float)h);
            }
        }
        #pragma unroll
        for (int ct = 0; ct < CT; ct++) {
            const f16x8 ah = *(const f16x8*)(base + ct * 512 + l * 8);
            const f16x8 al = *(const f16x8*)(base + 8192 + ct * 512 + l * 8);
            #pragma unroll
            for (int st = 0; st < 2; st++) {
                acc[ct][st] = __builtin_amdgcn_mfma_f32_16x16x32_f16(ah, bh[st], acc[ct][st], 0, 0, 0);
                acc[ct][st] = __builtin_amdgcn_mfma_f32_16x16x32_f16(ah, bl[st], acc[ct][st], 0, 0, 0);
                acc[ct][st] = __builtin_amdgcn_mfma_f32_16x16x32_f16(al, bh[st], acc[ct][st], 0, 0, 0);
            }
        }
    };

    loadEA(0);
    stage(0, sbuf[0]);
    __syncthreads();

    int cur = 0;
    for (int kc = 0; kc < NKC; kc += 2) {
        // even iter: consume A, prefetch into B at top
        if (kc + 1 < NKC) { loadEB(kc + 1); stage(kc + 1, sbuf[cur ^ 1]); }
        splitMfma(eA0, eA1, sbuf[cur]);
        __syncthreads();
        cur ^= 1;
        // odd iter: consume B, prefetch into A at top
        if (kc + 1 < NKC) {
            if (kc + 2 < NKC) { loadEA(kc + 2); stage(kc + 2, sbuf[cur ^ 1]); }
            splitMfma(eB0, eB1, sbuf[cur]);
            __syncthreads();
            cur ^= 1;
        }
    }

    // add WP and max over c  (c = ct*16 + lg*4 + r; token col = lr)
    #pragma unroll
    for (int st = 0; st < 2; st++) {
        const float* wrow = wpt + pid[st] * Cc + lg * 4;
        float mx = -3.4e38f;
        #pragma unroll
        for (int ct = 0; ct < CT; ct++) {
            const f32x4 wp = *(const f32x4*)(wrow + ct * 16);
            #pragma unroll
            for (int r = 0; r < 4; r++) mx = fmaxf(mx, acc[ct][st][r] + wp[r]);
        }
        mx = fmaxf(mx, __shfl_xor(mx, 16));
        mx = fmaxf(mx, __shfl_xor(mx, 32));
        if (lg == 0) {
            const int s = s0 + wv * 32 + st * 16 + lr;
            const float mk = mask[b * Ss + s];
            top[b * Ss + s] = mx * mk + (mk - 1.0f) * NEGV;
        }
    }
}

// ---------------- Pass 2: softmax over s ----------------
__global__ __launch_bounds__(256) void k_softmax(
    const float* __restrict__ top, float* __restrict__ probs)
{
    const int b = blockIdx.x, t = threadIdx.x;
    const float* row = top + (size_t)b * Ss;
    float v[8];
    #pragma unroll
    for (int i = 0; i < 8; i++) v[i] = row[t + 256 * i];

    float mx = v[0];
    #pragma unroll
    for (int i = 1; i < 8; i++) mx = fmaxf(mx, v[i]);
    #pragma unroll
    for (int o = 32; o >= 1; o >>= 1) mx = fmaxf(mx, __shfl_xor(mx, o));

    __shared__ float redm[4], reds[4];
    const int w = t >> 6, ln = t & 63;
    if (ln == 0) redm[w] = mx;
    __syncthreads();
    mx = fmaxf(fmaxf(redm[0], redm[1]), fmaxf(redm[2], redm[3]));

    float sum = 0.f;
    #pragma unroll
    for (int i = 0; i < 8; i++) { v[i] = expf(v[i] - mx); sum += v[i]; }
    #pragma unroll
    for (int o = 32; o >= 1; o >>= 1) sum += __shfl_xor(sum, o);
    if (ln == 0) reds[w] = sum;
    __syncthreads();
    sum = reds[0] + reds[1] + reds[2] + reds[3];

    const float inv = 1.0f / sum;
    #pragma unroll
    for (int i = 0; i < 8; i++) probs[(size_t)b * Ss + t + 256 * i] = v[i] * inv;
}

// ---------------- Pass 3: partial context sums ----------------
__global__ __launch_bounds__(256) void k_ctx_partial(
    const float* __restrict__ embeds, const float* __restrict__ probs,
    float* __restrict__ partial)   // [B][NSPLIT][D]
{
    const int b  = blockIdx.x / NSPLIT;
    const int sp = blockIdx.x % NSPLIT;
    const int d  = threadIdx.x * 4;
    const float* base = embeds + ((size_t)b * Ss + sp * SCHUNK) * Dd;
    const float* prow = probs + (size_t)b * Ss + sp * SCHUNK;
    float4 acc = make_float4(0.f, 0.f, 0.f, 0.f);
    for (int s = 0; s < SCHUNK; s++) {
        const float p = prow[s];
        float4 e = *(const float4*)(base + (size_t)s * Dd + d);
        acc.x = fmaf(p, e.x, acc.x);
        acc.y = fmaf(p, e.y, acc.y);
        acc.z = fmaf(p, e.z, acc.z);
        acc.w = fmaf(p, e.w, acc.w);
    }
    *(float4*)(partial + ((size_t)(b * NSPLIT + sp)) * Dd + d) = acc;
}

// ---------------- Pass 4: reduce partials, apply tok_diag ----------------
__global__ __launch_bounds__(256) void k_ctx_reduce(
    const float* __restrict__ partial, const float* __restrict__ tok_diag,
    float* __restrict__ out)  // [B][D]
{
    const int b = blockIdx.x;
    const int d = threadIdx.x * 4;
    float4 acc = make_float4(0.f, 0.f, 0.f, 0.f);
    #pragma unroll
    for (int sp = 0; sp < NSPLIT; sp++) {
        float4 v = *(const float4*)(partial + ((size_t)(b * NSPLIT + sp)) * Dd + d);
        acc.x += v.x; acc.y += v.y; acc.z += v.z; acc.w += v.w;
    }
    float4 td = *(const float4*)(tok_diag + d);
    float4 o = make_float4(acc.x * td.x, acc.y * td.y, acc.z * td.z, acc.w * td.w);
    *(float4*)(out + (size_t)b * Dd + d) = o;
}

extern "C" void kernel_launch(void* const* d_in, const int* in_sizes, int n_in,
                              void* d_out, int out_size, void* d_ws, size_t ws_size,
                              hipStream_t stream) {
    const float* embeds    = (const float*)d_in[0];
    const float* mask      = (const float*)d_in[1];
    const float* latent    = (const float*)d_in[2];
    const float* att_diag  = (const float*)d_in[3];
    const float* tok_diag  = (const float*)d_in[4];
    const float* pos_table = (const float*)d_in[5];
    const float* tok_mult  = (const float*)d_in[6];
    const int*   rel_ids   = (const int*)d_in[7];
    float* out = (float*)d_out;

    char* ws = (char*)d_ws;
    _Float16* w      = (_Float16*)(ws);              // 1 MB
    float*    wpt    = (float*)(ws + 1048576);       // 256 KB (135168 used)
    float*    top    = (float*)(ws + 1310720);       // 256 KB
    float*    probs  = (float*)(ws + 1572864);       // 256 KB
    float*    partial= (float*)(ws + 1835008);       // 2 MB

    k_prep_w<<<(Cc * Dd) / 256, 256, 0, stream>>>(latent, att_diag, tok_mult, w);
    k_wp<<<132, 256, 0, stream>>>(latent, att_diag, pos_table, wpt);
    k_scores_mfma<<<(Bb * Ss) / 128, 256, 0, stream>>>(
        embeds, mask, rel_ids, w, wpt, top);
    k_softmax<<<Bb, 256, 0, stream>>>(top, probs);
    k_ctx_partial<<<Bb * NSPLIT, 256, 0, stream>>>(embeds, probs, partial);
    k_ctx_reduce<<<Bb, 256, 0, stream>>>(partial, tok_diag, out);
}

// Round 8
// 140.129 us; speedup vs baseline: 1.3308x; 1.3308x over previous
//
#include <hip/hip_runtime.h>
#include <hip/hip_bf16.h>

// B=32, S=2048, D=1024, C=256
//   top[b,s] = max_c sum_d (latent[c,d]*att_diag[d]) * (tm*embeds[b,s,d] + pos_table[rel+64,d])
//   p = softmax_s(top*m + (m-1)*NEG);  ctx[b,d] = tok_diag[d] * sum_s embeds*p
//
// Pass 1 (R4-proven core, verbatim): split-fp16 MFMA (hh + h*lo + lo*h),
// W = latent*att_diag pre-split hi/lo fp16 per-kc 32KB chunks; 256 thr /
// 4 waves / 128 tokens per block; wave owns 16 c-tiles x 2 token sets;
// W staged via global_load_lds into dbuf LDS (64KB, 2 blocks/CU).
// NEW (flash-style): pass-1 epilogue also computes block-local softmax
// partials  P[b,blk,d] = sum_{s in blk} exp(l_s - M_b) * e[s,d]  (embeds
// tile is L2-hot), eliminating the 268MB HBM re-read of ctx_partial.
// k_msum: per-b global max M, Z, coef[b,blk] = exp(M_b - M)/Z.
// k_combine: out[b,d] = tok_diag[d] * sum_blk coef * P.
//
// ws: w 1MB | top 256K | partial 2M | mblk 2K | coef 2K

#define HC 64
#define NEGV 1000000000000.0f

constexpr int Bb = 32, Ss = 2048, Dd = 1024, Cc = 256;
constexpr int NKC = 32;                 // k-chunks of 32
constexpr int CT = Cc / 16;             // 16 c-tiles
constexpr int NBLK = 16;                // 128-token blocks per batch

typedef _Float16 f16x8 __attribute__((ext_vector_type(8)));
typedef float    f32x4 __attribute__((ext_vector_type(4)));

// ---------------- Pass 0: W -> per-kc fragment chunks, fp16 hi/lo ----------
// layout: w[kc][part][ct][lane][8], chunk = 16384 f16 = 32KB
// A-frag map: lane = (c%16) + 16*g holds A[c][k = kc*32 + 8g + i]
__global__ __launch_bounds__(256) void k_prep_w(
    const float* __restrict__ latent, const float* __restrict__ att_diag,
    _Float16* __restrict__ w)
{
    const int idx = blockIdx.x * 256 + threadIdx.x;   // c*Dd + k
    const int c = idx >> 10, k = idx & 1023;
    const float wv = latent[idx] * att_diag[k];
    const _Float16 h  = (_Float16)wv;
    const _Float16 lo = (_Float16)(wv - (float)h);
    const int kc = k >> 5, g = (k >> 3) & 3, i = k & 7;
    const int lane = (c & 15) + 16 * g, ct = c >> 4;
    const size_t base = (size_t)kc * 16384 + (size_t)ct * 512 + lane * 8 + i;
    w[base]        = h;
    w[base + 8192] = lo;
}

// ---------------- Pass 1: scores via MFMA, max, block-local ctx partial ----
__global__ __launch_bounds__(256, 2) void k_scores_mfma(
    const float* __restrict__ embeds,    // [B][S][D]
    const float* __restrict__ mask,      // [B][S]
    const float* __restrict__ pos_table, // [132][D]
    const float* __restrict__ tok_mult,  // [1]
    const int*   __restrict__ rel_ids,   // [B][S]
    const _Float16* __restrict__ w,      // [NKC][2][CT][64][8]
    float* __restrict__ top,             // [B][S]
    float* __restrict__ partial,         // [B][NBLK][D]
    float* __restrict__ mblk)            // [B][NBLK]
{
    __shared__ _Float16 sbuf[2][16384];  // 2 x 32KB
    __shared__ float l_sh[128];
    __shared__ float w_sh[128];
    __shared__ float red2[2];

    const int t  = threadIdx.x;
    const int wv = t >> 6;      // wave 0..3
    const int l  = t & 63;
    const int lr = l & 15;      // token within set / output col
    const int lg = l >> 4;      // k-group

    const int b     = blockIdx.x >> 4;   // 16 blocks of 128 tokens per batch
    const int blk16 = blockIdx.x & 15;
    const int s0    = blk16 * 128;

    const float tm = tok_mult[0];

    const float* erow[2];
    const float* prow[2];
    #pragma unroll
    for (int st = 0; st < 2; st++) {
        const int tok = s0 + wv * 32 + st * 16 + lr;
        erow[st] = embeds + ((size_t)b * Ss + tok) * Dd;
        prow[st] = pos_table + (size_t)(rel_ids[b * Ss + tok] + HC) * Dd;
    }

    f32x4 acc[CT][2];
    #pragma unroll
    for (int ct = 0; ct < CT; ct++)
        #pragma unroll
        for (int st = 0; st < 2; st++) acc[ct][st] = (f32x4){0.f, 0.f, 0.f, 0.f};

    // raw e/p prefetch registers (one kc ahead)
    f32x4 e0[2], e1[2], p0[2], p1[2];
    auto loadEP = [&](int kc) {
        const int k0 = kc * 32 + lg * 8;
        #pragma unroll
        for (int st = 0; st < 2; st++) {
            e0[st] = *(const f32x4*)(erow[st] + k0);
            e1[st] = *(const f32x4*)(erow[st] + k0 + 4);
            p0[st] = *(const f32x4*)(prow[st] + k0);
            p1[st] = *(const f32x4*)(prow[st] + k0 + 4);
        }
    };

    // stage one 32KB W chunk: 32 wave-chunks of 1KB (8 per wave)
    auto stage = [&](int kc, _Float16* dst) {
        const _Float16* src = w + (size_t)kc * 16384;
        #pragma unroll
        for (int i = 0; i < 8; i++) {
            const int off = (i * 4 + wv) << 9;   // elems; 1KB chunks
            __builtin_amdgcn_global_load_lds(
                (const __attribute__((address_space(1))) void*)(src + off + l * 8),
                (__attribute__((address_space(3))) void*)(dst + off),
                16, 0, 0);
        }
    };

    loadEP(0);
    stage(0, sbuf[0]);
    __syncthreads();   // drains vmcnt: stage(0) + loadEP(0) complete

    int cur = 0;
    for (int kc = 0; kc < NKC; kc++) {
        if (kc + 1 < NKC) stage(kc + 1, sbuf[cur ^ 1]);

        // build current B frags (hi/lo fp16) from prefetched raws
        f16x8 bh[2], bl[2];
        #pragma unroll
        for (int st = 0; st < 2; st++) {
            float e[8], p[8];
            *(f32x4*)&e[0] = e0[st]; *(f32x4*)&e[4] = e1[st];
            *(f32x4*)&p[0] = p0[st]; *(f32x4*)&p[4] = p1[st];
            #pragma unroll
            for (int i = 0; i < 8; i++) {
                const float x = fmaf(tm, e[i], p[i]);
                const _Float16 h = (_Float16)x;
                bh[st][i] = h;
                bl[st][i] = (_Float16)(x - (float)h);
            }
        }
        if (kc + 1 < NKC) loadEP(kc + 1);   // issue next-kc e/p early

        const _Float16* base = sbuf[cur];
        #pragma unroll
        for (int ct = 0; ct < CT; ct++) {
            const f16x8 ah = *(const f16x8*)(base + ct * 512 + l * 8);
            const f16x8 al = *(const f16x8*)(base + 8192 + ct * 512 + l * 8);
            #pragma unroll
            for (int st = 0; st < 2; st++) {
                acc[ct][st] = __builtin_amdgcn_mfma_f32_16x16x32_f16(ah, bh[st], acc[ct][st], 0, 0, 0);
                acc[ct][st] = __builtin_amdgcn_mfma_f32_16x16x32_f16(ah, bl[st], acc[ct][st], 0, 0, 0);
                acc[ct][st] = __builtin_amdgcn_mfma_f32_16x16x32_f16(al, bh[st], acc[ct][st], 0, 0, 0);
            }
        }
        __syncthreads();   // stage(kc+1) done; all waves done reading sbuf[cur]
        cur ^= 1;
    }

    // masked logit per token; stash in LDS for the flash epilogue
    #pragma unroll
    for (int st = 0; st < 2; st++) {
        float mx = acc[0][st][0];
        #pragma unroll
        for (int ct = 0; ct < CT; ct++)
            #pragma unroll
            for (int r = 0; r < 4; r++) mx = fmaxf(mx, acc[ct][st][r]);
        mx = fmaxf(mx, __shfl_xor(mx, 16));
        mx = fmaxf(mx, __shfl_xor(mx, 32));
        if (lg == 0) {
            const int si = wv * 32 + st * 16 + lr;   // token within block
            const int s  = s0 + si;
            const float mk = mask[b * Ss + s];
            const float lv = mx * mk + (mk - 1.0f) * NEGV;
            top[b * Ss + s] = lv;
            l_sh[si] = lv;
        }
    }
    __syncthreads();

    // block max M_b over the 128 logits
    if (t < 128) {
        float v = l_sh[t];
        #pragma unroll
        for (int o = 32; o >= 1; o >>= 1) v = fmaxf(v, __shfl_xor(v, o));
        if ((t & 63) == 0) red2[t >> 6] = v;
    }
    __syncthreads();
    const float Mb = fmaxf(red2[0], red2[1]);
    if (t < 128) w_sh[t] = expf(l_sh[t] - Mb);
    __syncthreads();

    // block-local ctx partial: P[d] = sum_s w_sh[s] * e[s0+s][d]  (L2-hot)
    {
        const float* eb = embeds + ((size_t)b * Ss + s0) * Dd + t * 4;
        f32x4 ca = (f32x4){0.f, 0.f, 0.f, 0.f};
        #pragma unroll 8
        for (int s = 0; s < 128; s++) {
            const float wgt = w_sh[s];
            const f32x4 ev = *(const f32x4*)(eb + (size_t)s * Dd);
            ca[0] = fmaf(wgt, ev[0], ca[0]);
            ca[1] = fmaf(wgt, ev[1], ca[1]);
            ca[2] = fmaf(wgt, ev[2], ca[2]);
            ca[3] = fmaf(wgt, ev[3], ca[3]);
        }
        *(f32x4*)(partial + ((size_t)(b * NBLK + blk16)) * Dd + t * 4) = ca;
        if (t == 0) mblk[b * NBLK + blk16] = Mb;
    }
}

// ---------------- Pass 2: per-b global max/Z -> per-block coefficients ----
__global__ __launch_bounds__(256) void k_msum(
    const float* __restrict__ top, const float* __restrict__ mblk,
    float* __restrict__ coef)
{
    const int b = blockIdx.x, t = threadIdx.x;
    const float* row = top + (size_t)b * Ss;
    float v[8];
    #pragma unroll
    for (int i = 0; i < 8; i++) v[i] = row[t + 256 * i];

    float mx = v[0];
    #pragma unroll
    for (int i = 1; i < 8; i++) mx = fmaxf(mx, v[i]);
    #pragma unroll
    for (int o = 32; o >= 1; o >>= 1) mx = fmaxf(mx, __shfl_xor(mx, o));

    __shared__ float redm[4], reds[4];
    const int w = t >> 6, ln = t & 63;
    if (ln == 0) redm[w] = mx;
    __syncthreads();
    mx = fmaxf(fmaxf(redm[0], redm[1]), fmaxf(redm[2], redm[3]));

    float sum = 0.f;
    #pragma unroll
    for (int i = 0; i < 8; i++) sum += expf(v[i] - mx);
    #pragma unroll
    for (int o = 32; o >= 1; o >>= 1) sum += __shfl_xor(sum, o);
    if (ln == 0) reds[w] = sum;
    __syncthreads();
    sum = reds[0] + reds[1] + reds[2] + reds[3];

    if (t < NBLK) {
        coef[b * NBLK + t] = expf(mblk[b * NBLK + t] - mx) / sum;
    }
}

// ---------------- Pass 3: combine partials, apply tok_diag ----------------
__global__ __launch_bounds__(256) void k_combine(
    const float* __restrict__ partial, const float* __restrict__ coef,
    const float* __restrict__ tok_diag, float* __restrict__ out)
{
    const int b = blockIdx.x;
    const int d = threadIdx.x * 4;
    f32x4 a = (f32x4){0.f, 0.f, 0.f, 0.f};
    #pragma unroll
    for (int j = 0; j < NBLK; j++) {
        const float cf = coef[b * NBLK + j];
        const f32x4 p = *(const f32x4*)(partial + ((size_t)(b * NBLK + j)) * Dd + d);
        a[0] = fmaf(cf, p[0], a[0]);
        a[1] = fmaf(cf, p[1], a[1]);
        a[2] = fmaf(cf, p[2], a[2]);
        a[3] = fmaf(cf, p[3], a[3]);
    }
    const f32x4 td = *(const f32x4*)(tok_diag + d);
    f32x4 o = a * td;
    *(f32x4*)(out + (size_t)b * Dd + d) = o;
}

extern "C" void kernel_launch(void* const* d_in, const int* in_sizes, int n_in,
                              void* d_out, int out_size, void* d_ws, size_t ws_size,
                              hipStream_t stream) {
    const float* embeds    = (const float*)d_in[0];
    const float* mask      = (const float*)d_in[1];
    const float* latent    = (const float*)d_in[2];
    const float* att_diag  = (const float*)d_in[3];
    const float* tok_diag  = (const float*)d_in[4];
    const float* pos_table = (const float*)d_in[5];
    const float* tok_mult  = (const float*)d_in[6];
    const int*   rel_ids   = (const int*)d_in[7];
    float* out = (float*)d_out;

    char* ws = (char*)d_ws;
    _Float16* w      = (_Float16*)(ws);              // 1 MB
    float*    top    = (float*)(ws + 1048576);       // 256 KB
    float*    partial= (float*)(ws + 1310720);       // 2 MB
    float*    mblk   = (float*)(ws + 3407872);       // 2 KB
    float*    coef   = (float*)(ws + 3409920);       // 2 KB

    k_prep_w<<<(Cc * Dd) / 256, 256, 0, stream>>>(latent, att_diag, w);
    k_scores_mfma<<<(Bb * Ss) / 128, 256, 0, stream>>>(
        embeds, mask, pos_table, tok_mult, rel_ids, w, top, partial, mblk);
    k_msum<<<Bb, 256, 0, stream>>>(top, mblk, coef);
    k_combine<<<Bb, 256, 0, stream>>>(partial, coef, tok_diag, out);
}